// Round 5
// baseline (232.936 us; speedup 1.0000x reference)
//
#include <hip/hip_runtime.h>
#include <hip/hip_bf16.h>
#include <stdint.h>
#include <stddef.h>

// ---------------------------------------------------------------------------
// Quantized LSTM cell (B=4096, I=H=1024) with JAX threefry noise reproduction.
//
// gates = qS8(input) @ (Wih^T + n0) + b_ih + nb0 + qS8(hx) @ (Whh^T + n1) + b_hh + nb1
// ONE bf16 MFMA GEMM, M=N=K=4096:
//   A  [4096][2048] = [qS8(input) | qS8(hx)]          (exact in bf16)
//   B^T[4096][4096] = rows k<2048: bf16_hi(Weff), k>=2048: bf16_lo(Weff)
//   B columns PERMUTED: col' = 4*h + gate  -> LSTM epilogue fused into GEMM.
//
// GEMM main loop: EXACT round-2 structure (129us, MfmaUtil 45%):
// 256x256 tile, BK=32, 8 waves (2Mx4N), 4-deep LDS pipeline (128KB),
// 4 barriers/K-tile, compiler-counted lgkmcnt before MFMA (no explicit
// lgkmcnt(0) drain!), counted vmcnt(4), XOR-swizzled LDS, setprio.
// ---------------------------------------------------------------------------

#define PART 1

typedef __attribute__((ext_vector_type(8))) short bf16x8;
typedef __attribute__((ext_vector_type(4))) float f32x4;

#define BATCH 4096

// ---- workspace layout (bytes) ----
#define WS_A_OFF    ((size_t)0)                 // ushort[4096*2048]   16 MiB
#define WS_B_OFF    ((size_t)16 << 20)          // ushort[4096*4096]   32 MiB
#define WS_BIAS_OFF ((size_t)48 << 20)          // float [4096]
#define WS_MAX_OFF  (WS_BIAS_OFF + 16384)       // uint32[4]

// ---------------- threefry2x32 (exact JAX algorithm) ----------------
__host__ __device__ inline void tf2x32(uint32_t k0, uint32_t k1,
                                       uint32_t x0, uint32_t x1,
                                       uint32_t &o0, uint32_t &o1)
{
  const uint32_t k2 = k0 ^ k1 ^ 0x1BD11BDAu;
#define TFR(r) { x0 += x1; x1 = (x1 << (r)) | (x1 >> (32 - (r))); x1 ^= x0; }
  x0 += k0; x1 += k1;
  TFR(13) TFR(15) TFR(26) TFR(6)
  x0 += k1; x1 += k2 + 1u;
  TFR(17) TFR(29) TFR(16) TFR(24)
  x0 += k2; x1 += k0 + 2u;
  TFR(13) TFR(15) TFR(26) TFR(6)
  x0 += k0; x1 += k1 + 3u;
  TFR(17) TFR(29) TFR(16) TFR(24)
  x0 += k1; x1 += k2 + 4u;
  TFR(13) TFR(15) TFR(26) TFR(6)
  x0 += k2; x1 += k0 + 5u;
#undef TFR
  o0 = x0; o1 = x1;
}

__device__ inline uint32_t jax_bits32(uint32_t k0, uint32_t k1, uint32_t i, uint32_t size)
{
#if PART
  uint32_t a, b;
  tf2x32(k0, k1, 0u, i, a, b);
  return a ^ b;
#else
  uint32_t half = size >> 1, a, b;
  if (i < half) { tf2x32(k0, k1, i, i + half, a, b); return a; }
  tf2x32(k0, k1, i - half, i, a, b); return b;
#endif
}

// uniform(-1+2^-24, 1) -> sqrt(2)*erfinv(u), XLA f32 ErfInv (Giles) polynomial
__device__ inline float bits_to_normal(uint32_t bits)
{
  float f = __uint_as_float((bits >> 9) | 0x3F800000u) - 1.0f;
  const float lo = -0x1.fffffep-1f;
  float u = fmaxf(lo, f * 2.0f + lo);
  float w = -log1pf(-u * u);
  float p;
  if (w < 5.0f) {
    w -= 2.5f;
    p = 2.81022636e-08f;
    p = fmaf(p, w, 3.43273939e-07f);
    p = fmaf(p, w, -3.5233877e-06f);
    p = fmaf(p, w, -4.39150654e-06f);
    p = fmaf(p, w, 0.00021858087f);
    p = fmaf(p, w, -0.00125372503f);
    p = fmaf(p, w, -0.00417768164f);
    p = fmaf(p, w, 0.246640727f);
    p = fmaf(p, w, 1.50140941f);
  } else {
    w = sqrtf(w) - 3.0f;
    p = -0.000200214257f;
    p = fmaf(p, w, 0.000100950558f);
    p = fmaf(p, w, 0.00134934322f);
    p = fmaf(p, w, -0.00367342844f);
    p = fmaf(p, w, 0.00573950773f);
    p = fmaf(p, w, -0.0076224613f);
    p = fmaf(p, w, 0.00943887047f);
    p = fmaf(p, w, 1.00167406f);
    p = fmaf(p, w, 2.83297682f);
  }
  return 0x1.6a09e6p+0f * (p * u);
}

// ---------------- quantization helpers ----------------
__device__ inline float quantS8(float x)
{
  x = fminf(fmaxf(x, -0.9921875f), 0.9921875f);
  return rintf(x * 128.0f) * 0.0078125f;
}
__device__ inline float quantU8(float x)
{
  x = fminf(fmaxf(x, 0.0f), 1.0f);
  return rintf(x * 256.0f) * 0.00390625f;
}
__device__ inline float sigmoid_xla(float x) { return 0.5f + 0.5f * tanhf(0.5f * x); }

__device__ inline unsigned short f2bf(float x)
{
  uint32_t b = __float_as_uint(x);
  return (unsigned short)((b + 0x7FFFu + ((b >> 16) & 1u)) >> 16);
}
__device__ inline float bf2f(unsigned short u) { return __uint_as_float(((uint32_t)u) << 16); }

__device__ inline float dec_max(uint32_t u)
{
  uint32_t bits = (u & 0x80000000u) ? (u ^ 0x80000000u) : ~u;
  return __uint_as_float(bits);
}

// ---------------- small kernels ----------------
__global__ void init_max(uint32_t* mx)
{
  if (threadIdx.x < 4) mx[threadIdx.x] = 0u;
}

__global__ void kmax(const float4* __restrict__ a, int n4, uint32_t* __restrict__ out)
{
  float m = -3.4e38f;
  for (int i = blockIdx.x * blockDim.x + threadIdx.x; i < n4; i += gridDim.x * blockDim.x) {
    float4 v = a[i];
    m = fmaxf(fmaxf(m, fmaxf(v.x, v.y)), fmaxf(v.z, v.w));
  }
  for (int off = 32; off; off >>= 1) m = fmaxf(m, __shfl_down(m, off, 64));
  __shared__ float sm[4];
  if ((threadIdx.x & 63) == 0) sm[threadIdx.x >> 6] = m;
  __syncthreads();
  if (threadIdx.x == 0) {
    float bm = sm[0];
    for (int w = 1; w < (int)(blockDim.x >> 6); ++w) bm = fmaxf(bm, sm[w]);
    uint32_t bits = __float_as_uint(bm);
    uint32_t enc = (bits & 0x80000000u) ? ~bits : (bits | 0x80000000u);
    atomicMax(out, enc);
  }
}

__global__ void build_A(const float4* __restrict__ in, const float4* __restrict__ hx,
                        unsigned short* __restrict__ A)
{
  int t = blockIdx.x * 256 + threadIdx.x;
  int b = t >> 9;
  int kq = t & 511;
  float4 v = (kq < 256) ? in[b * 256 + kq] : hx[b * 256 + (kq - 256)];
  unsigned short o[4];
  o[0] = f2bf(quantS8(v.x)); o[1] = f2bf(quantS8(v.y));
  o[2] = f2bf(quantS8(v.z)); o[3] = f2bf(quantS8(v.w));
  *reinterpret_cast<uint64_t*>(A + (size_t)t * 4) = *reinterpret_cast<uint64_t*>(o);
}

// B^T with PERMUTED columns: original gate-col n (g=n>>10, h=n&1023) stored
// at row n' = 4h+g.  kc<2048: hi(Weff), kc>=2048: lo residual.
__global__ void build_B(const float* __restrict__ wih, const float* __restrict__ whh,
                        unsigned short* __restrict__ B, const uint32_t* __restrict__ mxenc,
                        uint32_t kih0, uint32_t kih1, uint32_t khh0, uint32_t khh1)
{
  uint32_t t = blockIdx.x * 256u + threadIdx.x;
  uint32_t arr = t >> 22;
  uint32_t r = t & 4194303u;
  uint32_t k = r & 1023u;
  uint32_t n = r >> 10;                       // original gate column
  const float* w = arr ? whh : wih;
  float mx = dec_max(mxenc[arr]);
  uint32_t key0 = arr ? khh0 : kih0, key1 = arr ? khh1 : kih1;
  uint32_t i = k * 4096u + n;                 // noise flat index (orig layout)
  float nrm = bits_to_normal(jax_bits32(key0, key1, i, 4194304u));
  float weff = w[(size_t)n * 1024u + k] + (nrm * mx) * 0.05f;
  unsigned short hi = f2bf(weff);
  unsigned short lob = f2bf(weff - bf2f(hi));
  uint32_t np = (n & 1023u) * 4u + (n >> 10); // permuted column
  size_t base = (size_t)np * 4096u + (arr ? 1024u : 0u) + k;
  B[base] = hi;
  B[base + 2048u] = lob;
}

__global__ void build_bias(const float* __restrict__ bih, const float* __restrict__ bhh,
                           float* __restrict__ biasE, const uint32_t* __restrict__ mxenc,
                           uint32_t kbi0, uint32_t kbi1, uint32_t kbh0, uint32_t kbh1)
{
  uint32_t j = blockIdx.x * 256u + threadIdx.x;
  if (j >= 4096u) return;
  float mi = dec_max(mxenc[2]), mh = dec_max(mxenc[3]);
  float ni = (bits_to_normal(jax_bits32(kbi0, kbi1, j, 4096u)) * mi) * 0.05f;
  float nh = (bits_to_normal(jax_bits32(kbh0, kbh1, j, 4096u)) * mh) * 0.05f;
  biasE[(j & 1023u) * 4u + (j >> 10)] = ((bih[j] + ni) + bhh[j]) + nh;
}

// ---------------- deep-pipelined MFMA GEMM + fused LSTM epilogue ------------
__device__ __forceinline__ void gload_lds16(const void* g, void* l)
{
  __builtin_amdgcn_global_load_lds((__attribute__((address_space(1))) void*)g,
                                   (__attribute__((address_space(3))) void*)l, 16, 0, 0);
}

#define VM4  asm volatile("s_waitcnt vmcnt(4)" ::: "memory")
#define VM0  asm volatile("s_waitcnt vmcnt(0)" ::: "memory")
#define NOVM

// EXACT round-2 K-tile structure (measured 129us / MfmaUtil 45%):
// reads(8) + stage-A -> barrier -> MFMA-lo(16, compiler-counted lgkm)
// -> barrier -> reads(4) + stage-B -> barrier -> MFMA-hi(16) -> vmcnt(4)
// -> barrier.
#define TILE_ONE(t_, DO_STAGE_, VM_ASM_)                                          \
  {                                                                               \
    const int buf_ = (t_) & 3;                                                    \
    const unsigned char* pa_ = lds + buf_ * 32768 + aoff;                         \
    const unsigned char* pb_ = lds + buf_ * 32768 + boff;                         \
    bf16x8 bfr_[4], af_[4];                                                       \
    _Pragma("unroll") for (int n_ = 0; n_ < 4; ++n_)                              \
      bfr_[n_] = *(const bf16x8*)(pb_ + n_ * 1024);                               \
    _Pragma("unroll") for (int m_ = 0; m_ < 4; ++m_)                              \
      af_[m_] = *(const bf16x8*)(pa_ + m_ * 1024);                                \
    if (DO_STAGE_) {                                                              \
      const int ts_ = (t_) + 2;                                                   \
      unsigned char* la_ = lds + (ts_ & 3) * 32768;                               \
      const int ka_ = (ts_ * 32) & 2047;                                          \
      gload_lds16(Ar0 + ka_, la_ + tid * 16);                                     \
      gload_lds16(Ar1 + ka_, la_ + 8192 + tid * 16);                              \
    }                                                                             \
    __builtin_amdgcn_s_barrier();                                                 \
    __builtin_amdgcn_sched_barrier(0);                                            \
    __builtin_amdgcn_s_setprio(1);                                                \
    _Pragma("unroll") for (int m_ = 0; m_ < 4; ++m_)                              \
      _Pragma("unroll") for (int n_ = 0; n_ < 4; ++n_)                            \
        acc[m_][n_] = __builtin_amdgcn_mfma_f32_16x16x32_bf16(af_[m_], bfr_[n_],  \
                                                              acc[m_][n_], 0, 0, 0); \
    __builtin_amdgcn_s_setprio(0);                                                \
    __builtin_amdgcn_s_barrier();                                                 \
    __builtin_amdgcn_sched_barrier(0);                                            \
    _Pragma("unroll") for (int m_ = 0; m_ < 4; ++m_)                              \
      af_[m_] = *(const bf16x8*)(pa_ + (4 + m_) * 1024);                          \
    if (DO_STAGE_) {                                                              \
      const int ts_ = (t_) + 2;                                                   \
      unsigned char* lb_ = lds + (ts_ & 3) * 32768 + 16384;                       \
      const size_t kb_ = (size_t)ts_ * 32;                                        \
      gload_lds16(Br0 + kb_, lb_ + tid * 16);                                     \
      gload_lds16(Br1 + kb_, lb_ + 8192 + tid * 16);                              \
    }                                                                             \
    __builtin_amdgcn_s_barrier();                                                 \
    __builtin_amdgcn_sched_barrier(0);                                            \
    __builtin_amdgcn_s_setprio(1);                                                \
    _Pragma("unroll") for (int m_ = 0; m_ < 4; ++m_)                              \
      _Pragma("unroll") for (int n_ = 0; n_ < 4; ++n_)                            \
        acc[4 + m_][n_] = __builtin_amdgcn_mfma_f32_16x16x32_bf16(af_[m_], bfr_[n_], \
                                                              acc[4 + m_][n_], 0, 0, 0); \
    __builtin_amdgcn_s_setprio(0);                                                \
    VM_ASM_;                                                                      \
    __builtin_amdgcn_s_barrier();                                                 \
    __builtin_amdgcn_sched_barrier(0);                                            \
  }

__global__ __launch_bounds__(512, 2) void gemm_gates(
    const unsigned short* __restrict__ A,   // [4096][2048] bf16 bits
    const unsigned short* __restrict__ B,   // [4096][4096] bf16 bits, permuted cols
    const float* __restrict__ bias,         // [4096] permuted
    const float* __restrict__ cx,           // [4096][1024]
    float* __restrict__ hy,                 // [4096][1024]
    float* __restrict__ cy)                 // [4096][1024]
{
  extern __shared__ unsigned char lds[];    // 128KB
  const int tid  = threadIdx.x;
  const int lane = tid & 63;
  const int wave = tid >> 6;
  const int wr = wave >> 2;                 // 0..1  (M)
  const int wc = wave & 3;                  // 0..3  (N)

  const int bid = blockIdx.x;
  const int wg  = (bid & 7) * 32 + (bid >> 3);
  const int brow = (wg & 15) * 256;
  const int bcol = (wg >> 4) * 256;

  // staging source (inverse-swizzled): chunk c -> p=c>>3, lc=(c&7)^(p&7)
  int sr0, sk0, sr1, sk1;
  {
    int c = tid, p = c >> 3, lc = (c & 7) ^ (p & 7);
    sr0 = p * 2 + (lc >> 2); sk0 = (lc & 3) * 8;
    c = tid + 512; p = c >> 3; lc = (c & 7) ^ (p & 7);
    sr1 = p * 2 + (lc >> 2); sk1 = (lc & 3) * 8;
  }
  const unsigned short* Ar0 = A + (size_t)(brow + sr0) * 2048 + sk0;
  const unsigned short* Ar1 = A + (size_t)(brow + sr1) * 2048 + sk1;
  const unsigned short* Br0 = B + (size_t)(bcol + sr0) * 4096 + sk0;
  const unsigned short* Br1 = B + (size_t)(bcol + sr1) * 4096 + sk1;

  const int lrh = (lane & 15) >> 1;
  const int chk = ((((lane & 1) << 2) | (lane >> 4)) ^ lrh);
  const int aoff = wr * 8192 + lrh * 128 + chk * 16;
  const int boff = 16384 + wc * 4096 + lrh * 128 + chk * 16;

  f32x4 acc[8][4] = {};

  // prologue: stage tiles 0,1 (per-thread order A,A',B,B')
#pragma unroll
  for (int tt = 0; tt < 2; ++tt) {
    unsigned char* la = lds + tt * 32768;
    const int ka = tt * 32;
    gload_lds16(Ar0 + ka, la + tid * 16);
    gload_lds16(Ar1 + ka, la + 8192 + tid * 16);
    gload_lds16(Br0 + (size_t)(tt * 32), la + 16384 + tid * 16);
    gload_lds16(Br1 + (size_t)(tt * 32), la + 16384 + 8192 + tid * 16);
  }
  VM4;
  __builtin_amdgcn_s_barrier();
  __builtin_amdgcn_sched_barrier(0);

#pragma unroll 1
  for (int t = 0; t < 126; ++t) {
    TILE_ONE(t, 1, VM4);
  }
  TILE_ONE(126, 0, VM0);
  TILE_ONE(127, 0, NOVM);

  // ---- fused LSTM epilogue (verified in rounds 3-4) ----
  // acc[q][n] row = brow + wr*128 + q*16 + (lane>>4)*4 + r
  //           col = bcol + wc*64 + n*16 + (lane&15)   (permuted: col = 4h+g)
  float* LT = (float*)lds;
  const int col_local0 = wc * 64 + (lane & 15);
  const int lrow = (lane >> 4) << 2;
  const int h = tid & 63;
  const int hg = (bcol >> 2) + h;

#pragma unroll
  for (int hh = 0; hh < 2; ++hh) {
    __syncthreads();                       // previous half's reads done
#pragma unroll
    for (int m = 0; m < 4; ++m) {
#pragma unroll
      for (int n = 0; n < 4; ++n) {
        const int cl = col_local0 + n * 16;
        const float bv = bias[bcol + cl];
        const int lr0 = wr * 64 + m * 16 + lrow;
#pragma unroll
        for (int r = 0; r < 4; ++r)
          LT[(lr0 + r) * 256 + cl] = acc[hh * 4 + m][n][r] + bv;
      }
    }
    __syncthreads();
#pragma unroll
    for (int i = 0; i < 16; ++i) {
      const int lr = (tid >> 6) * 16 + i;                       // 0..127
      const int grow = brow + ((lr >> 6) << 7) + hh * 64 + (lr & 63);
      const float4 q = *(const float4*)(LT + lr * 256 + 4 * h); // (in,fg,cell,out)
      const size_t oidx = (size_t)grow * 1024 + hg;
      float ing = quantU8(sigmoid_xla(q.x));
      float fg  = quantU8(sigmoid_xla(q.y));
      float cg  = quantS8(tanhf(q.z));
      float og  = quantU8(sigmoid_xla(q.w));
      float c0  = cx[oidx];
      float cyv = quantS8((quantS8(fg * c0) + quantS8(ing * cg)) * 0.5f);
      float hyv = quantS8(og * quantS8(tanhf(cyv * 2.0f)));
      hy[oidx] = hyv;
      cy[oidx] = cyv;
    }
  }
}

// ---------------- host ----------------
extern "C" void kernel_launch(void* const* d_in, const int* in_sizes, int n_in,
                              void* d_out, int out_size, void* d_ws, size_t ws_size,
                              hipStream_t stream)
{
  const float* input = (const float*)d_in[0];
  const float* hx    = (const float*)d_in[1];
  const float* cx    = (const float*)d_in[2];
  const float* wih   = (const float*)d_in[3];
  const float* whh   = (const float*)d_in[4];
  const float* bih   = (const float*)d_in[5];
  const float* bhh   = (const float*)d_in[6];
  (void)in_sizes; (void)n_in; (void)ws_size;

  uint8_t* ws = (uint8_t*)d_ws;
  unsigned short* A   = (unsigned short*)(ws + WS_A_OFF);
  unsigned short* B   = (unsigned short*)(ws + WS_B_OFF);
  float* biasE        = (float*)(ws + WS_BIAS_OFF);
  uint32_t* mx        = (uint32_t*)(ws + WS_MAX_OFF);

  uint32_t nk[4][2];
#if PART
  for (int i = 0; i < 4; ++i) tf2x32(0u, 42u, 0u, (uint32_t)i, nk[i][0], nk[i][1]);
#else
  {
    uint32_t w0[4], w1[4];
    for (int i = 0; i < 4; ++i) tf2x32(0u, 42u, (uint32_t)i, (uint32_t)(i + 4), w0[i], w1[i]);
    uint32_t out8[8] = {w0[0], w0[1], w0[2], w0[3], w1[0], w1[1], w1[2], w1[3]};
    for (int i = 0; i < 4; ++i) { nk[i][0] = out8[2 * i]; nk[i][1] = out8[2 * i + 1]; }
  }
#endif

  init_max<<<1, 64, 0, stream>>>(mx);
  kmax<<<1024, 256, 0, stream>>>((const float4*)wih, 1048576, mx + 0);
  kmax<<<1024, 256, 0, stream>>>((const float4*)whh, 1048576, mx + 1);
  kmax<<<4, 256, 0, stream>>>((const float4*)bih, 1024, mx + 2);
  kmax<<<4, 256, 0, stream>>>((const float4*)bhh, 1024, mx + 3);

  build_A<<<8192, 256, 0, stream>>>((const float4*)input, (const float4*)hx, A);
  build_B<<<32768, 256, 0, stream>>>(wih, whh, B, mx, nk[0][0], nk[0][1], nk[1][0], nk[1][1]);
  build_bias<<<16, 256, 0, stream>>>(bih, bhh, biasE, mx, nk[2][0], nk[2][1], nk[3][0], nk[3][1]);

  float* hy = (float*)d_out;
  float* cyp = hy + (size_t)BATCH * 1024;

  (void)hipFuncSetAttribute((const void*)gemm_gates,
                            hipFuncAttributeMaxDynamicSharedMemorySize, 131072);
  gemm_gates<<<dim3(256), dim3(512), 131072, stream>>>(A, B, biasE, cx, hy, cyp);
}

// Round 6
// 214.864 us; speedup vs baseline: 1.0841x; 1.0841x over previous
//
#include <hip/hip_runtime.h>
#include <hip/hip_bf16.h>
#include <stdint.h>
#include <stddef.h>

// ---------------------------------------------------------------------------
// Quantized LSTM cell (B=4096, I=H=1024) with JAX threefry noise reproduction.
//
// gates = qS8(input) @ (Wih^T + n0) + b_ih + nb0 + qS8(hx) @ (Whh^T + n1) + b_hh + nb1
// ONE bf16 MFMA GEMM over real-K=2048:
//   A  [4096][2048] = [qS8(input) | qS8(hx)]          (exact in bf16)
//   B^T[4096][4096] = cols k<2048: bf16_hi(Weff), k>=2048: bf16_lo(Weff)
//   Each K-tile multiplies ONE staged A unit against BOTH B_hi and B_lo
//   (A read/staged once -> 33% less LDS read traffic, 25% less staging).
//   B columns PERMUTED: col' = 4*h + gate  -> LSTM epilogue fused into GEMM.
//
// GEMM: 256x256 tile, BK=32(real), 8 waves (2Mx4N), 2x48KB LDS double buffer,
// R2-proven phase skeleton (reads||stage -> barrier -> 16 MFMA -> barrier),
// XOR-swizzled LDS (0 bank conflicts), setprio around MFMA.
// ---------------------------------------------------------------------------

#define PART 1

typedef __attribute__((ext_vector_type(8))) short bf16x8;
typedef __attribute__((ext_vector_type(4))) float f32x4;

#define BATCH 4096

// ---- workspace layout (bytes) ----
#define WS_A_OFF    ((size_t)0)                 // ushort[4096*2048]   16 MiB
#define WS_B_OFF    ((size_t)16 << 20)          // ushort[4096*4096]   32 MiB
#define WS_BIAS_OFF ((size_t)48 << 20)          // float [4096]
#define WS_MAX_OFF  (WS_BIAS_OFF + 16384)       // uint32[4]

// ---------------- threefry2x32 (exact JAX algorithm) ----------------
__host__ __device__ inline void tf2x32(uint32_t k0, uint32_t k1,
                                       uint32_t x0, uint32_t x1,
                                       uint32_t &o0, uint32_t &o1)
{
  const uint32_t k2 = k0 ^ k1 ^ 0x1BD11BDAu;
#define TFR(r) { x0 += x1; x1 = (x1 << (r)) | (x1 >> (32 - (r))); x1 ^= x0; }
  x0 += k0; x1 += k1;
  TFR(13) TFR(15) TFR(26) TFR(6)
  x0 += k1; x1 += k2 + 1u;
  TFR(17) TFR(29) TFR(16) TFR(24)
  x0 += k2; x1 += k0 + 2u;
  TFR(13) TFR(15) TFR(26) TFR(6)
  x0 += k0; x1 += k1 + 3u;
  TFR(17) TFR(29) TFR(16) TFR(24)
  x0 += k1; x1 += k2 + 4u;
  TFR(13) TFR(15) TFR(26) TFR(6)
  x0 += k2; x1 += k0 + 5u;
#undef TFR
  o0 = x0; o1 = x1;
}

__device__ inline uint32_t jax_bits32(uint32_t k0, uint32_t k1, uint32_t i, uint32_t size)
{
#if PART
  uint32_t a, b;
  tf2x32(k0, k1, 0u, i, a, b);
  return a ^ b;
#else
  uint32_t half = size >> 1, a, b;
  if (i < half) { tf2x32(k0, k1, i, i + half, a, b); return a; }
  tf2x32(k0, k1, i - half, i, a, b); return b;
#endif
}

// uniform(-1+2^-24, 1) -> sqrt(2)*erfinv(u), XLA f32 ErfInv (Giles) polynomial
__device__ inline float bits_to_normal(uint32_t bits)
{
  float f = __uint_as_float((bits >> 9) | 0x3F800000u) - 1.0f;
  const float lo = -0x1.fffffep-1f;
  float u = fmaxf(lo, f * 2.0f + lo);
  float w = -log1pf(-u * u);
  float p;
  if (w < 5.0f) {
    w -= 2.5f;
    p = 2.81022636e-08f;
    p = fmaf(p, w, 3.43273939e-07f);
    p = fmaf(p, w, -3.5233877e-06f);
    p = fmaf(p, w, -4.39150654e-06f);
    p = fmaf(p, w, 0.00021858087f);
    p = fmaf(p, w, -0.00125372503f);
    p = fmaf(p, w, -0.00417768164f);
    p = fmaf(p, w, 0.246640727f);
    p = fmaf(p, w, 1.50140941f);
  } else {
    w = sqrtf(w) - 3.0f;
    p = -0.000200214257f;
    p = fmaf(p, w, 0.000100950558f);
    p = fmaf(p, w, 0.00134934322f);
    p = fmaf(p, w, -0.00367342844f);
    p = fmaf(p, w, 0.00573950773f);
    p = fmaf(p, w, -0.0076224613f);
    p = fmaf(p, w, 0.00943887047f);
    p = fmaf(p, w, 1.00167406f);
    p = fmaf(p, w, 2.83297682f);
  }
  return 0x1.6a09e6p+0f * (p * u);
}

// ---------------- quantization helpers ----------------
__device__ inline float quantS8(float x)
{
  x = fminf(fmaxf(x, -0.9921875f), 0.9921875f);
  return rintf(x * 128.0f) * 0.0078125f;
}
__device__ inline float quantU8(float x)
{
  x = fminf(fmaxf(x, 0.0f), 1.0f);
  return rintf(x * 256.0f) * 0.00390625f;
}
__device__ inline float sigmoid_xla(float x) { return 0.5f + 0.5f * tanhf(0.5f * x); }

__device__ inline unsigned short f2bf(float x)
{
  uint32_t b = __float_as_uint(x);
  return (unsigned short)((b + 0x7FFFu + ((b >> 16) & 1u)) >> 16);
}
__device__ inline float bf2f(unsigned short u) { return __uint_as_float(((uint32_t)u) << 16); }

__device__ inline float dec_max(uint32_t u)
{
  uint32_t bits = (u & 0x80000000u) ? (u ^ 0x80000000u) : ~u;
  return __uint_as_float(bits);
}

// ---------------- fused small kernels ----------------
__global__ void init_max(uint32_t* mx)
{
  if (threadIdx.x < 4) mx[threadIdx.x] = 0u;
}

// One launch for all 4 max-reductions.
__global__ void kmax_all(const float4* __restrict__ wih, const float4* __restrict__ whh,
                         const float4* __restrict__ bih, const float4* __restrict__ bhh,
                         uint32_t* __restrict__ mx)
{
  const int blk = blockIdx.x;
  const float4* src; int n4, bl, nb; uint32_t* out;
  if (blk < 1024)      { src = wih; n4 = 1048576; bl = blk;        nb = 1024; out = mx + 0; }
  else if (blk < 2048) { src = whh; n4 = 1048576; bl = blk - 1024; nb = 1024; out = mx + 1; }
  else if (blk < 2052) { src = bih; n4 = 1024;    bl = blk - 2048; nb = 4;    out = mx + 2; }
  else                 { src = bhh; n4 = 1024;    bl = blk - 2052; nb = 4;    out = mx + 3; }

  float m = -3.4e38f;
  for (int i = bl * 256 + threadIdx.x; i < n4; i += nb * 256) {
    float4 v = src[i];
    m = fmaxf(fmaxf(m, fmaxf(v.x, v.y)), fmaxf(v.z, v.w));
  }
  for (int off = 32; off; off >>= 1) m = fmaxf(m, __shfl_down(m, off, 64));
  __shared__ float sm[4];
  if ((threadIdx.x & 63) == 0) sm[threadIdx.x >> 6] = m;
  __syncthreads();
  if (threadIdx.x == 0) {
    float bm = fmaxf(fmaxf(sm[0], sm[1]), fmaxf(sm[2], sm[3]));
    uint32_t bits = __float_as_uint(bm);
    uint32_t enc = (bits & 0x80000000u) ? ~bits : (bits | 0x80000000u);
    atomicMax(out, enc);
  }
}

// One launch for build_B + build_A + build_bias.
// blocks [0,32768): B;  [32768,40960): A;  [40960,40976): bias.
__global__ void build_all(const float* __restrict__ wih, const float* __restrict__ whh,
                          const float4* __restrict__ in, const float4* __restrict__ hxp,
                          const float* __restrict__ bih, const float* __restrict__ bhh,
                          unsigned short* __restrict__ A, unsigned short* __restrict__ B,
                          float* __restrict__ biasE, const uint32_t* __restrict__ mxenc,
                          uint32_t kih0, uint32_t kih1, uint32_t khh0, uint32_t khh1,
                          uint32_t kbi0, uint32_t kbi1, uint32_t kbh0, uint32_t kbh1)
{
  const uint32_t blk = blockIdx.x;
  if (blk < 32768u) {
    // ---- build_B: B^T permuted cols, hi at kc<2048, lo residual at kc>=2048
    uint32_t t = blk * 256u + threadIdx.x;
    uint32_t arr = t >> 22;
    uint32_t r = t & 4194303u;
    uint32_t k = r & 1023u;
    uint32_t n = r >> 10;                       // original gate column
    const float* w = arr ? whh : wih;
    float mx = dec_max(mxenc[arr]);
    uint32_t key0 = arr ? khh0 : kih0, key1 = arr ? khh1 : kih1;
    uint32_t i = k * 4096u + n;                 // noise flat index (orig layout)
    float nrm = bits_to_normal(jax_bits32(key0, key1, i, 4194304u));
    float weff = w[(size_t)n * 1024u + k] + (nrm * mx) * 0.05f;
    unsigned short hi = f2bf(weff);
    unsigned short lob = f2bf(weff - bf2f(hi));
    uint32_t np = (n & 1023u) * 4u + (n >> 10); // permuted column
    size_t base = (size_t)np * 4096u + (arr ? 1024u : 0u) + k;
    B[base] = hi;
    B[base + 2048u] = lob;
  } else if (blk < 40960u) {
    // ---- build_A: A[b][k] = bf16(qS8(...)), exact in bf16
    int t = (int)(blk - 32768u) * 256 + threadIdx.x;
    int b = t >> 9;
    int kq = t & 511;
    float4 v = (kq < 256) ? in[b * 256 + kq] : hxp[b * 256 + (kq - 256)];
    unsigned short o[4];
    o[0] = f2bf(quantS8(v.x)); o[1] = f2bf(quantS8(v.y));
    o[2] = f2bf(quantS8(v.z)); o[3] = f2bf(quantS8(v.w));
    *reinterpret_cast<uint64_t*>(A + (size_t)t * 4) = *reinterpret_cast<uint64_t*>(o);
  } else {
    // ---- build_bias (permuted)
    uint32_t j = (blk - 40960u) * 256u + threadIdx.x;
    float mi = dec_max(mxenc[2]), mh = dec_max(mxenc[3]);
    float ni = (bits_to_normal(jax_bits32(kbi0, kbi1, j, 4096u)) * mi) * 0.05f;
    float nh = (bits_to_normal(jax_bits32(kbh0, kbh1, j, 4096u)) * mh) * 0.05f;
    biasE[(j & 1023u) * 4u + (j >> 10)] = ((bih[j] + ni) + bhh[j]) + nh;
  }
}

// ---------------- MFMA GEMM (A-shared hi/lo) + fused LSTM epilogue ----------
__device__ __forceinline__ void gload_lds16(const void* g, void* l)
{
  __builtin_amdgcn_global_load_lds((__attribute__((address_space(1))) void*)g,
                                   (__attribute__((address_space(3))) void*)l, 16, 0, 0);
}

#define VM0  asm volatile("s_waitcnt vmcnt(0)" ::: "memory")
#define NOVM
#define SBAR __builtin_amdgcn_s_barrier()
#define SCB  __builtin_amdgcn_sched_barrier(0)

#define BUFSZ 49152   // A(16K) + Bhi(16K) + Blo(16K)

// One real-K tile (32 cols of A, 32 hi + 32 lo cols of B) = 64 MFMA.
// R2-proven skeleton per phase: [reads || stage] -> barrier -> MFMA cluster
// (compiler-counted lgkm) -> barrier.  A frags reused for hi AND lo halves.
#define TILE_ONE(t_, DO_STAGE_, VM_ASM_)                                          \
  {                                                                               \
    const int buf_ = (t_) & 1;                                                    \
    const unsigned char* pa_  = lds + buf_ * BUFSZ + aoff;                        \
    const unsigned char* pbh_ = lds + buf_ * BUFSZ + 16384 + boffU;               \
    const unsigned char* pbl_ = lds + buf_ * BUFSZ + 32768 + boffU;               \
    bf16x8 bh_[4], bl_[4], afL_[4], afH_[4];                                      \
    /* phase 0: reads bhi(4)+afL(4); stage all 6 units of tile t+1 */             \
    _Pragma("unroll") for (int n_ = 0; n_ < 4; ++n_)                              \
      bh_[n_] = *(const bf16x8*)(pbh_ + n_ * 1024);                               \
    _Pragma("unroll") for (int m_ = 0; m_ < 4; ++m_)                              \
      afL_[m_] = *(const bf16x8*)(pa_ + m_ * 1024);                               \
    if (DO_STAGE_) {                                                              \
      const int ts_ = (t_) + 1;                                                   \
      unsigned char* la_ = lds + (ts_ & 1) * BUFSZ;                               \
      const int ka_ = ts_ * 32;                                                   \
      gload_lds16(Ar0 + ka_, la_ + tid * 16);                                     \
      gload_lds16(Ar1 + ka_, la_ + 8192 + tid * 16);                              \
      gload_lds16(Br0 + ka_, la_ + 16384 + tid * 16);                             \
      gload_lds16(Br1 + ka_, la_ + 16384 + 8192 + tid * 16);                      \
      gload_lds16(Br0 + 2048 + ka_, la_ + 32768 + tid * 16);                      \
      gload_lds16(Br1 + 2048 + ka_, la_ + 32768 + 8192 + tid * 16);               \
    }                                                                             \
    SBAR; SCB;                                                                    \
    __builtin_amdgcn_s_setprio(1);                                                \
    _Pragma("unroll") for (int m_ = 0; m_ < 4; ++m_)                              \
      _Pragma("unroll") for (int n_ = 0; n_ < 4; ++n_)                            \
        acc[m_][n_] = __builtin_amdgcn_mfma_f32_16x16x32_bf16(afL_[m_], bh_[n_],  \
                                                              acc[m_][n_], 0, 0, 0); \
    __builtin_amdgcn_s_setprio(0);                                                \
    SBAR; SCB;                                                                    \
    /* phase 1: reads afH(4) */                                                   \
    _Pragma("unroll") for (int m_ = 0; m_ < 4; ++m_)                              \
      afH_[m_] = *(const bf16x8*)(pa_ + (4 + m_) * 1024);                         \
    SBAR; SCB;                                                                    \
    __builtin_amdgcn_s_setprio(1);                                                \
    _Pragma("unroll") for (int m_ = 0; m_ < 4; ++m_)                              \
      _Pragma("unroll") for (int n_ = 0; n_ < 4; ++n_)                            \
        acc[4 + m_][n_] = __builtin_amdgcn_mfma_f32_16x16x32_bf16(afH_[m_], bh_[n_], \
                                                              acc[4 + m_][n_], 0, 0, 0); \
    __builtin_amdgcn_s_setprio(0);                                                \
    SBAR; SCB;                                                                    \
    /* phase 2: reads blo(4); then 32 MFMA reusing afL/afH */                     \
    _Pragma("unroll") for (int n_ = 0; n_ < 4; ++n_)                              \
      bl_[n_] = *(const bf16x8*)(pbl_ + n_ * 1024);                               \
    SBAR; SCB;                                                                    \
    __builtin_amdgcn_s_setprio(1);                                                \
    _Pragma("unroll") for (int m_ = 0; m_ < 4; ++m_)                              \
      _Pragma("unroll") for (int n_ = 0; n_ < 4; ++n_)                            \
        acc[m_][n_] = __builtin_amdgcn_mfma_f32_16x16x32_bf16(afL_[m_], bl_[n_],  \
                                                              acc[m_][n_], 0, 0, 0); \
    _Pragma("unroll") for (int m_ = 0; m_ < 4; ++m_)                              \
      _Pragma("unroll") for (int n_ = 0; n_ < 4; ++n_)                            \
        acc[4 + m_][n_] = __builtin_amdgcn_mfma_f32_16x16x32_bf16(afH_[m_], bl_[n_], \
                                                              acc[4 + m_][n_], 0, 0, 0); \
    __builtin_amdgcn_s_setprio(0);                                                \
    VM_ASM_;                                                                      \
    SBAR; SCB;                                                                    \
  }

#define LTS 272   // epilogue LDS row stride in floats (breaks 4-way write conflict)

__global__ __launch_bounds__(512, 2) void gemm_gates(
    const unsigned short* __restrict__ A,   // [4096][2048] bf16 bits
    const unsigned short* __restrict__ B,   // [4096][4096] bf16 bits, permuted cols
    const float* __restrict__ bias,         // [4096] permuted
    const float* __restrict__ cx,           // [4096][1024]
    float* __restrict__ hy,                 // [4096][1024]
    float* __restrict__ cy)                 // [4096][1024]
{
  extern __shared__ unsigned char lds[];    // 139264 B
  const int tid  = threadIdx.x;
  const int lane = tid & 63;
  const int wave = tid >> 6;
  const int wr = wave >> 2;                 // 0..1  (M)
  const int wc = wave & 3;                  // 0..3  (N)

  const int bid = blockIdx.x;
  const int wg  = (bid & 7) * 32 + (bid >> 3);
  const int brow = (wg & 15) * 256;
  const int bcol = (wg >> 4) * 256;

  // staging source (inverse-swizzled): chunk c -> p=c>>3, lc=(c&7)^(p&7)
  int sr0, sk0, sr1, sk1;
  {
    int c = tid, p = c >> 3, lc = (c & 7) ^ (p & 7);
    sr0 = p * 2 + (lc >> 2); sk0 = (lc & 3) * 8;
    c = tid + 512; p = c >> 3; lc = (c & 7) ^ (p & 7);
    sr1 = p * 2 + (lc >> 2); sk1 = (lc & 3) * 8;
  }
  const unsigned short* Ar0 = A + (size_t)(brow + sr0) * 2048 + sk0;
  const unsigned short* Ar1 = A + (size_t)(brow + sr1) * 2048 + sk1;
  const unsigned short* Br0 = B + (size_t)(bcol + sr0) * 4096 + sk0;
  const unsigned short* Br1 = B + (size_t)(bcol + sr1) * 4096 + sk1;

  const int lrh = (lane & 15) >> 1;
  const int chk = ((((lane & 1) << 2) | (lane >> 4)) ^ lrh);
  const int aoff  = wr * 8192 + lrh * 128 + chk * 16;
  const int boffU = wc * 4096 + lrh * 128 + chk * 16;

  f32x4 acc[8][4] = {};

  // prologue: stage tile 0 (A, A', Bhi, Bhi', Blo, Blo')
  gload_lds16(Ar0, lds + tid * 16);
  gload_lds16(Ar1, lds + 8192 + tid * 16);
  gload_lds16(Br0, lds + 16384 + tid * 16);
  gload_lds16(Br1, lds + 16384 + 8192 + tid * 16);
  gload_lds16(Br0 + 2048, lds + 32768 + tid * 16);
  gload_lds16(Br1 + 2048, lds + 32768 + 8192 + tid * 16);
  VM0;
  SBAR; SCB;

#pragma unroll 1
  for (int t = 0; t < 63; ++t) {
    TILE_ONE(t, 1, VM0);
  }
  TILE_ONE(63, 0, NOVM);

  // ---- fused LSTM epilogue ----
  // acc[q][n] row = brow + wr*128 + q*16 + (lane>>4)*4 + r
  //           col = bcol + wc*64 + n*16 + (lane&15)   (permuted: col = 4h+g)
  float* LT = (float*)lds;
  const int col_local0 = wc * 64 + (lane & 15);
  const int lrow = (lane >> 4) << 2;
  const int h = tid & 63;
  const int hg = (bcol >> 2) + h;

#pragma unroll
  for (int hh = 0; hh < 2; ++hh) {
    __syncthreads();                       // previous half's reads done
#pragma unroll
    for (int m = 0; m < 4; ++m) {
#pragma unroll
      for (int n = 0; n < 4; ++n) {
        const int cl = col_local0 + n * 16;
        const float bv = bias[bcol + cl];
        const int lr0 = wr * 64 + m * 16 + lrow;
#pragma unroll
        for (int r = 0; r < 4; ++r)
          LT[(lr0 + r) * LTS + cl] = acc[hh * 4 + m][n][r] + bv;
      }
    }
    __syncthreads();
#pragma unroll
    for (int i = 0; i < 16; ++i) {
      const int lr = (tid >> 6) * 16 + i;                       // 0..127
      const int grow = brow + ((lr >> 6) << 7) + hh * 64 + (lr & 63);
      const float4 q = *(const float4*)(LT + lr * LTS + 4 * h); // (in,fg,cell,out)
      const size_t oidx = (size_t)grow * 1024 + hg;
      float ing = quantU8(sigmoid_xla(q.x));
      float fg  = quantU8(sigmoid_xla(q.y));
      float cg  = quantS8(tanhf(q.z));
      float og  = quantU8(sigmoid_xla(q.w));
      float c0  = cx[oidx];
      float cyv = quantS8((quantS8(fg * c0) + quantS8(ing * cg)) * 0.5f);
      float hyv = quantS8(og * quantS8(tanhf(cyv * 2.0f)));
      hy[oidx] = hyv;
      cy[oidx] = cyv;
    }
  }
}

// ---------------- host ----------------
extern "C" void kernel_launch(void* const* d_in, const int* in_sizes, int n_in,
                              void* d_out, int out_size, void* d_ws, size_t ws_size,
                              hipStream_t stream)
{
  const float* input = (const float*)d_in[0];
  const float* hx    = (const float*)d_in[1];
  const float* cx    = (const float*)d_in[2];
  const float* wih   = (const float*)d_in[3];
  const float* whh   = (const float*)d_in[4];
  const float* bih   = (const float*)d_in[5];
  const float* bhh   = (const float*)d_in[6];
  (void)in_sizes; (void)n_in; (void)ws_size;

  uint8_t* ws = (uint8_t*)d_ws;
  unsigned short* A   = (unsigned short*)(ws + WS_A_OFF);
  unsigned short* B   = (unsigned short*)(ws + WS_B_OFF);
  float* biasE        = (float*)(ws + WS_BIAS_OFF);
  uint32_t* mx        = (uint32_t*)(ws + WS_MAX_OFF);

  uint32_t nk[4][2];
#if PART
  for (int i = 0; i < 4; ++i) tf2x32(0u, 42u, 0u, (uint32_t)i, nk[i][0], nk[i][1]);
#else
  {
    uint32_t w0[4], w1[4];
    for (int i = 0; i < 4; ++i) tf2x32(0u, 42u, (uint32_t)i, (uint32_t)(i + 4), w0[i], w1[i]);
    uint32_t out8[8] = {w0[0], w0[1], w0[2], w0[3], w1[0], w1[1], w1[2], w1[3]};
    for (int i = 0; i < 4; ++i) { nk[i][0] = out8[2 * i]; nk[i][1] = out8[2 * i + 1]; }
  }
#endif

  init_max<<<1, 64, 0, stream>>>(mx);
  kmax_all<<<2056, 256, 0, stream>>>((const float4*)wih, (const float4*)whh,
                                     (const float4*)bih, (const float4*)bhh, mx);
  build_all<<<40976, 256, 0, stream>>>(wih, whh, (const float4*)input, (const float4*)hx,
                                       bih, bhh, A, B, biasE, mx,
                                       nk[0][0], nk[0][1], nk[1][0], nk[1][1],
                                       nk[2][0], nk[2][1], nk[3][0], nk[3][1]);

  float* hy = (float*)d_out;
  float* cyp = hy + (size_t)BATCH * 1024;

  (void)hipFuncSetAttribute((const void*)gemm_gates,
                            hipFuncAttributeMaxDynamicSharedMemorySize, 139264);
  gemm_gates<<<dim3(256), dim3(512), 139264, stream>>>(A, B, biasE, cx, hy, cyp);
}

// Round 7
// 190.480 us; speedup vs baseline: 1.2229x; 1.1280x over previous
//
#include <hip/hip_runtime.h>
#include <hip/hip_bf16.h>
#include <stdint.h>
#include <stddef.h>

// ---------------------------------------------------------------------------
// Quantized LSTM cell (B=4096, I=H=1024) with JAX threefry noise reproduction.
//
// gates = qS8(input) @ (Wih^T + n0) + b_ih + nb0 + qS8(hx) @ (Whh^T + n1) + b_hh + nb1
// ONE bf16 MFMA GEMM over real-K=2048:
//   A  [4096][2048] = [qS8(input) | qS8(hx)]          (exact in bf16)
//   B^T[4096][4096] = cols k<2048: bf16_hi(Weff), k>=2048: bf16_lo(Weff)
//   Each K-tile multiplies ONE staged A unit against BOTH B_hi and B_lo.
//   B columns PERMUTED: col' = 4*h + gate  -> LSTM epilogue fused into GEMM.
//
// GEMM: 256x256 tile, BK=32(real), 8 waves (2Mx4N), THREE 48KB LDS buffers,
// stage t+2 during t, counted vmcnt(6) at tile end (no full drain in loop),
// R2-proven phase skeleton, XOR-swizzled LDS, setprio around MFMA.
// Epilogue: hardware v_exp_f32/v_rcp_f32 activations (no lib tanhf).
// ---------------------------------------------------------------------------

#define PART 1

typedef __attribute__((ext_vector_type(8))) short bf16x8;
typedef __attribute__((ext_vector_type(4))) float f32x4;

#define BATCH 4096

// ---- workspace layout (bytes) ----
#define WS_A_OFF    ((size_t)0)                 // ushort[4096*2048]   16 MiB
#define WS_B_OFF    ((size_t)16 << 20)          // ushort[4096*4096]   32 MiB
#define WS_BIAS_OFF ((size_t)48 << 20)          // float [4096]
#define WS_MAX_OFF  (WS_BIAS_OFF + 16384)       // uint32[4]

// ---------------- threefry2x32 (exact JAX algorithm) ----------------
__host__ __device__ inline void tf2x32(uint32_t k0, uint32_t k1,
                                       uint32_t x0, uint32_t x1,
                                       uint32_t &o0, uint32_t &o1)
{
  const uint32_t k2 = k0 ^ k1 ^ 0x1BD11BDAu;
#define TFR(r) { x0 += x1; x1 = (x1 << (r)) | (x1 >> (32 - (r))); x1 ^= x0; }
  x0 += k0; x1 += k1;
  TFR(13) TFR(15) TFR(26) TFR(6)
  x0 += k1; x1 += k2 + 1u;
  TFR(17) TFR(29) TFR(16) TFR(24)
  x0 += k2; x1 += k0 + 2u;
  TFR(13) TFR(15) TFR(26) TFR(6)
  x0 += k0; x1 += k1 + 3u;
  TFR(17) TFR(29) TFR(16) TFR(24)
  x0 += k1; x1 += k2 + 4u;
  TFR(13) TFR(15) TFR(26) TFR(6)
  x0 += k2; x1 += k0 + 5u;
#undef TFR
  o0 = x0; o1 = x1;
}

__device__ inline uint32_t jax_bits32(uint32_t k0, uint32_t k1, uint32_t i, uint32_t size)
{
#if PART
  uint32_t a, b;
  tf2x32(k0, k1, 0u, i, a, b);
  return a ^ b;
#else
  uint32_t half = size >> 1, a, b;
  if (i < half) { tf2x32(k0, k1, i, i + half, a, b); return a; }
  tf2x32(k0, k1, i - half, i, a, b); return b;
#endif
}

// uniform(-1+2^-24, 1) -> sqrt(2)*erfinv(u), XLA f32 ErfInv (Giles) polynomial
__device__ inline float bits_to_normal(uint32_t bits)
{
  float f = __uint_as_float((bits >> 9) | 0x3F800000u) - 1.0f;
  const float lo = -0x1.fffffep-1f;
  float u = fmaxf(lo, f * 2.0f + lo);
  float w = -log1pf(-u * u);
  float p;
  if (w < 5.0f) {
    w -= 2.5f;
    p = 2.81022636e-08f;
    p = fmaf(p, w, 3.43273939e-07f);
    p = fmaf(p, w, -3.5233877e-06f);
    p = fmaf(p, w, -4.39150654e-06f);
    p = fmaf(p, w, 0.00021858087f);
    p = fmaf(p, w, -0.00125372503f);
    p = fmaf(p, w, -0.00417768164f);
    p = fmaf(p, w, 0.246640727f);
    p = fmaf(p, w, 1.50140941f);
  } else {
    w = sqrtf(w) - 3.0f;
    p = -0.000200214257f;
    p = fmaf(p, w, 0.000100950558f);
    p = fmaf(p, w, 0.00134934322f);
    p = fmaf(p, w, -0.00367342844f);
    p = fmaf(p, w, 0.00573950773f);
    p = fmaf(p, w, -0.0076224613f);
    p = fmaf(p, w, 0.00943887047f);
    p = fmaf(p, w, 1.00167406f);
    p = fmaf(p, w, 2.83297682f);
  }
  return 0x1.6a09e6p+0f * (p * u);
}

// ---------------- quantization + fast activation helpers ----------------
__device__ inline float quantS8(float x)
{
  x = fminf(fmaxf(x, -0.9921875f), 0.9921875f);
  return rintf(x * 128.0f) * 0.0078125f;
}
__device__ inline float quantU8(float x)
{
  x = fminf(fmaxf(x, 0.0f), 1.0f);
  return rintf(x * 256.0f) * 0.00390625f;
}

#define LOG2E 1.44269504088896340736f
// sigmoid via hardware v_exp_f32 + v_rcp_f32 (branch-free, ~1ulp each)
__device__ inline float sigmoid_fast(float x)
{
  float e = __builtin_amdgcn_exp2f(x * -LOG2E);
  return __builtin_amdgcn_rcpf(1.0f + e);
}
// tanh via e = exp2(-2|x|*log2e); (1-e)/(1+e) with sign restore
__device__ inline float tanh_fast(float x)
{
  float a = fabsf(x);
  float e = __builtin_amdgcn_exp2f(a * (-2.0f * LOG2E));
  float t = (1.0f - e) * __builtin_amdgcn_rcpf(1.0f + e);
  return copysignf(t, x);
}

__device__ inline unsigned short f2bf(float x)
{
  uint32_t b = __float_as_uint(x);
  return (unsigned short)((b + 0x7FFFu + ((b >> 16) & 1u)) >> 16);
}
__device__ inline float bf2f(unsigned short u) { return __uint_as_float(((uint32_t)u) << 16); }

__device__ inline float dec_max(uint32_t u)
{
  uint32_t bits = (u & 0x80000000u) ? (u ^ 0x80000000u) : ~u;
  return __uint_as_float(bits);
}

// ---------------- fused small kernels ----------------
__global__ void init_max(uint32_t* mx)
{
  if (threadIdx.x < 4) mx[threadIdx.x] = 0u;
}

__global__ void kmax_all(const float4* __restrict__ wih, const float4* __restrict__ whh,
                         const float4* __restrict__ bih, const float4* __restrict__ bhh,
                         uint32_t* __restrict__ mx)
{
  const int blk = blockIdx.x;
  const float4* src; int n4, bl, nb; uint32_t* out;
  if (blk < 1024)      { src = wih; n4 = 1048576; bl = blk;        nb = 1024; out = mx + 0; }
  else if (blk < 2048) { src = whh; n4 = 1048576; bl = blk - 1024; nb = 1024; out = mx + 1; }
  else if (blk < 2052) { src = bih; n4 = 1024;    bl = blk - 2048; nb = 4;    out = mx + 2; }
  else                 { src = bhh; n4 = 1024;    bl = blk - 2052; nb = 4;    out = mx + 3; }

  float m = -3.4e38f;
  for (int i = bl * 256 + threadIdx.x; i < n4; i += nb * 256) {
    float4 v = src[i];
    m = fmaxf(fmaxf(m, fmaxf(v.x, v.y)), fmaxf(v.z, v.w));
  }
  for (int off = 32; off; off >>= 1) m = fmaxf(m, __shfl_down(m, off, 64));
  __shared__ float sm[4];
  if ((threadIdx.x & 63) == 0) sm[threadIdx.x >> 6] = m;
  __syncthreads();
  if (threadIdx.x == 0) {
    float bm = fmaxf(fmaxf(sm[0], sm[1]), fmaxf(sm[2], sm[3]));
    uint32_t bits = __float_as_uint(bm);
    uint32_t enc = (bits & 0x80000000u) ? ~bits : (bits | 0x80000000u);
    atomicMax(out, enc);
  }
}

// blocks [0,32768): B;  [32768,40960): A;  [40960,40976): bias.
__global__ void build_all(const float* __restrict__ wih, const float* __restrict__ whh,
                          const float4* __restrict__ in, const float4* __restrict__ hxp,
                          const float* __restrict__ bih, const float* __restrict__ bhh,
                          unsigned short* __restrict__ A, unsigned short* __restrict__ B,
                          float* __restrict__ biasE, const uint32_t* __restrict__ mxenc,
                          uint32_t kih0, uint32_t kih1, uint32_t khh0, uint32_t khh1,
                          uint32_t kbi0, uint32_t kbi1, uint32_t kbh0, uint32_t kbh1)
{
  const uint32_t blk = blockIdx.x;
  if (blk < 32768u) {
    uint32_t t = blk * 256u + threadIdx.x;
    uint32_t arr = t >> 22;
    uint32_t r = t & 4194303u;
    uint32_t k = r & 1023u;
    uint32_t n = r >> 10;                       // original gate column
    const float* w = arr ? whh : wih;
    float mx = dec_max(mxenc[arr]);
    uint32_t key0 = arr ? khh0 : kih0, key1 = arr ? khh1 : kih1;
    uint32_t i = k * 4096u + n;                 // noise flat index (orig layout)
    float nrm = bits_to_normal(jax_bits32(key0, key1, i, 4194304u));
    float weff = w[(size_t)n * 1024u + k] + (nrm * mx) * 0.05f;
    unsigned short hi = f2bf(weff);
    unsigned short lob = f2bf(weff - bf2f(hi));
    uint32_t np = (n & 1023u) * 4u + (n >> 10); // permuted column
    size_t base = (size_t)np * 4096u + (arr ? 1024u : 0u) + k;
    B[base] = hi;
    B[base + 2048u] = lob;
  } else if (blk < 40960u) {
    int t = (int)(blk - 32768u) * 256 + threadIdx.x;
    int b = t >> 9;
    int kq = t & 511;
    float4 v = (kq < 256) ? in[b * 256 + kq] : hxp[b * 256 + (kq - 256)];
    unsigned short o[4];
    o[0] = f2bf(quantS8(v.x)); o[1] = f2bf(quantS8(v.y));
    o[2] = f2bf(quantS8(v.z)); o[3] = f2bf(quantS8(v.w));
    *reinterpret_cast<uint64_t*>(A + (size_t)t * 4) = *reinterpret_cast<uint64_t*>(o);
  } else {
    uint32_t j = (blk - 40960u) * 256u + threadIdx.x;
    float mi = dec_max(mxenc[2]), mh = dec_max(mxenc[3]);
    float ni = (bits_to_normal(jax_bits32(kbi0, kbi1, j, 4096u)) * mi) * 0.05f;
    float nh = (bits_to_normal(jax_bits32(kbh0, kbh1, j, 4096u)) * mh) * 0.05f;
    biasE[(j & 1023u) * 4u + (j >> 10)] = ((bih[j] + ni) + bhh[j]) + nh;
  }
}

// ---------------- MFMA GEMM (A-shared hi/lo) + fused LSTM epilogue ----------
__device__ __forceinline__ void gload_lds16(const void* g, void* l)
{
  __builtin_amdgcn_global_load_lds((__attribute__((address_space(1))) void*)g,
                                   (__attribute__((address_space(3))) void*)l, 16, 0, 0);
}

#define VM6  asm volatile("s_waitcnt vmcnt(6)" ::: "memory")
#define VM0  asm volatile("s_waitcnt vmcnt(0)" ::: "memory")
#define NOVM
#define SBAR __builtin_amdgcn_s_barrier()
#define SCB  __builtin_amdgcn_sched_barrier(0)

#define BUFSZ 49152   // A(16K) + Bhi(16K) + Blo(16K)

// stage all 6 units of tile ts_ into buffer bi_
#define STAGE_A(ts_, bi_)                                                         \
    { unsigned char* la_ = lds + (bi_) * BUFSZ; const int ka_ = (ts_) * 32;       \
      gload_lds16(Ar0 + ka_, la_ + tid * 16);                                     \
      gload_lds16(Ar1 + ka_, la_ + 8192 + tid * 16); }
#define STAGE_BH(ts_, bi_)                                                        \
    { unsigned char* la_ = lds + (bi_) * BUFSZ; const int ka_ = (ts_) * 32;       \
      gload_lds16(Br0 + ka_, la_ + 16384 + tid * 16);                             \
      gload_lds16(Br1 + ka_, la_ + 16384 + 8192 + tid * 16); }
#define STAGE_BL(ts_, bi_)                                                        \
    { unsigned char* la_ = lds + (bi_) * BUFSZ; const int ka_ = (ts_) * 32;       \
      gload_lds16(Br0 + 2048 + ka_, la_ + 32768 + tid * 16);                      \
      gload_lds16(Br1 + 2048 + ka_, la_ + 32768 + 8192 + tid * 16); }

// One real-K tile (64 MFMA), buffer BUF_, staging tile t+2 into BUFN_.
// R2-proven skeleton: [reads || stage] -> barrier -> MFMA (counted lgkm) ->
// barrier -> ... ; counted vmcnt at tile end.
#define TILE_ONE(t_, BUF_, BUFN_, DO_STAGE_, VM_ASM_)                             \
  {                                                                               \
    const unsigned char* pa_  = lds + (BUF_) * BUFSZ + aoff;                      \
    const unsigned char* pbh_ = lds + (BUF_) * BUFSZ + 16384 + boffU;             \
    const unsigned char* pbl_ = lds + (BUF_) * BUFSZ + 32768 + boffU;             \
    bf16x8 bh_[4], bl_[4], afL_[4], afH_[4];                                      \
    _Pragma("unroll") for (int n_ = 0; n_ < 4; ++n_)                              \
      bh_[n_] = *(const bf16x8*)(pbh_ + n_ * 1024);                               \
    _Pragma("unroll") for (int m_ = 0; m_ < 4; ++m_)                              \
      afL_[m_] = *(const bf16x8*)(pa_ + m_ * 1024);                               \
    if (DO_STAGE_) STAGE_A((t_) + 2, BUFN_);                                      \
    SBAR; SCB;                                                                    \
    __builtin_amdgcn_s_setprio(1);                                                \
    _Pragma("unroll") for (int m_ = 0; m_ < 4; ++m_)                              \
      _Pragma("unroll") for (int n_ = 0; n_ < 4; ++n_)                            \
        acc[m_][n_] = __builtin_amdgcn_mfma_f32_16x16x32_bf16(afL_[m_], bh_[n_],  \
                                                              acc[m_][n_], 0, 0, 0); \
    __builtin_amdgcn_s_setprio(0);                                                \
    SBAR; SCB;                                                                    \
    _Pragma("unroll") for (int m_ = 0; m_ < 4; ++m_)                              \
      afH_[m_] = *(const bf16x8*)(pa_ + (4 + m_) * 1024);                         \
    if (DO_STAGE_) STAGE_BH((t_) + 2, BUFN_);                                     \
    SBAR; SCB;                                                                    \
    __builtin_amdgcn_s_setprio(1);                                                \
    _Pragma("unroll") for (int m_ = 0; m_ < 4; ++m_)                              \
      _Pragma("unroll") for (int n_ = 0; n_ < 4; ++n_)                            \
        acc[4 + m_][n_] = __builtin_amdgcn_mfma_f32_16x16x32_bf16(afH_[m_], bh_[n_], \
                                                              acc[4 + m_][n_], 0, 0, 0); \
    __builtin_amdgcn_s_setprio(0);                                                \
    SBAR; SCB;                                                                    \
    _Pragma("unroll") for (int n_ = 0; n_ < 4; ++n_)                              \
      bl_[n_] = *(const bf16x8*)(pbl_ + n_ * 1024);                               \
    if (DO_STAGE_) STAGE_BL((t_) + 2, BUFN_);                                     \
    SBAR; SCB;                                                                    \
    __builtin_amdgcn_s_setprio(1);                                                \
    _Pragma("unroll") for (int m_ = 0; m_ < 4; ++m_)                              \
      _Pragma("unroll") for (int n_ = 0; n_ < 4; ++n_)                            \
        acc[m_][n_] = __builtin_amdgcn_mfma_f32_16x16x32_bf16(afL_[m_], bl_[n_],  \
                                                              acc[m_][n_], 0, 0, 0); \
    _Pragma("unroll") for (int m_ = 0; m_ < 4; ++m_)                              \
      _Pragma("unroll") for (int n_ = 0; n_ < 4; ++n_)                            \
        acc[4 + m_][n_] = __builtin_amdgcn_mfma_f32_16x16x32_bf16(afH_[m_], bl_[n_], \
                                                              acc[4 + m_][n_], 0, 0, 0); \
    __builtin_amdgcn_s_setprio(0);                                                \
    VM_ASM_;                                                                      \
    SBAR; SCB;                                                                    \
  }

#define LTS 272   // epilogue LDS row stride in floats

__global__ __launch_bounds__(512, 2) void gemm_gates(
    const unsigned short* __restrict__ A,   // [4096][2048] bf16 bits
    const unsigned short* __restrict__ B,   // [4096][4096] bf16 bits, permuted cols
    const float* __restrict__ bias,         // [4096] permuted
    const float* __restrict__ cx,           // [4096][1024]
    float* __restrict__ hy,                 // [4096][1024]
    float* __restrict__ cy)                 // [4096][1024]
{
  extern __shared__ unsigned char lds[];    // 147456 B (3 x 48KB)
  const int tid  = threadIdx.x;
  const int lane = tid & 63;
  const int wave = tid >> 6;
  const int wr = wave >> 2;                 // 0..1  (M)
  const int wc = wave & 3;                  // 0..3  (N)

  const int bid = blockIdx.x;
  const int wg  = (bid & 7) * 32 + (bid >> 3);
  const int brow = (wg & 15) * 256;
  const int bcol = (wg >> 4) * 256;

  // staging source (inverse-swizzled): chunk c -> p=c>>3, lc=(c&7)^(p&7)
  int sr0, sk0, sr1, sk1;
  {
    int c = tid, p = c >> 3, lc = (c & 7) ^ (p & 7);
    sr0 = p * 2 + (lc >> 2); sk0 = (lc & 3) * 8;
    c = tid + 512; p = c >> 3; lc = (c & 7) ^ (p & 7);
    sr1 = p * 2 + (lc >> 2); sk1 = (lc & 3) * 8;
  }
  const unsigned short* Ar0 = A + (size_t)(brow + sr0) * 2048 + sk0;
  const unsigned short* Ar1 = A + (size_t)(brow + sr1) * 2048 + sk1;
  const unsigned short* Br0 = B + (size_t)(bcol + sr0) * 4096 + sk0;
  const unsigned short* Br1 = B + (size_t)(bcol + sr1) * 4096 + sk1;

  const int lrh = (lane & 15) >> 1;
  const int chk = ((((lane & 1) << 2) | (lane >> 4)) ^ lrh);
  const int aoff  = wr * 8192 + lrh * 128 + chk * 16;
  const int boffU = wc * 4096 + lrh * 128 + chk * 16;

  f32x4 acc[8][4] = {};

  // prologue: stage tile 0 -> buf0, tile 1 -> buf1; wait for tile 0 (vmcnt(6))
  STAGE_A(0, 0); STAGE_BH(0, 0); STAGE_BL(0, 0);
  STAGE_A(1, 1); STAGE_BH(1, 1); STAGE_BL(1, 1);
  VM6;
  SBAR; SCB;

#pragma unroll 1
  for (int tt = 0; tt < 60; tt += 3) {
    TILE_ONE(tt + 0, 0, 2, 1, VM6);
    TILE_ONE(tt + 1, 1, 0, 1, VM6);
    TILE_ONE(tt + 2, 2, 1, 1, VM6);
  }
  TILE_ONE(60, 0, 2, 1, VM6);
  TILE_ONE(61, 1, 0, 1, VM6);
  TILE_ONE(62, 2, 0, 0, VM0);
  TILE_ONE(63, 0, 0, 0, NOVM);

  // ---- fused LSTM epilogue (hardware-exp activations) ----
  // acc[q][n] row = brow + wr*128 + q*16 + (lane>>4)*4 + r
  //           col = bcol + wc*64 + n*16 + (lane&15)   (permuted: col = 4h+g)
  float* LT = (float*)lds;
  const int col_local0 = wc * 64 + (lane & 15);
  const int lrow = (lane >> 4) << 2;
  const int h = tid & 63;
  const int hg = (bcol >> 2) + h;

#pragma unroll
  for (int hh = 0; hh < 2; ++hh) {
    __syncthreads();                       // previous half's reads done
#pragma unroll
    for (int m = 0; m < 4; ++m) {
#pragma unroll
      for (int n = 0; n < 4; ++n) {
        const int cl = col_local0 + n * 16;
        const float bv = bias[bcol + cl];
        const int lr0 = wr * 64 + m * 16 + lrow;
#pragma unroll
        for (int r = 0; r < 4; ++r)
          LT[(lr0 + r) * LTS + cl] = acc[hh * 4 + m][n][r] + bv;
      }
    }
    __syncthreads();
#pragma unroll
    for (int i = 0; i < 16; ++i) {
      const int lr = (tid >> 6) * 16 + i;                       // 0..127
      const int grow = brow + ((lr >> 6) << 7) + hh * 64 + (lr & 63);
      const float4 q = *(const float4*)(LT + lr * LTS + 4 * h); // (in,fg,cell,out)
      const size_t oidx = (size_t)grow * 1024 + hg;
      float ing = quantU8(sigmoid_fast(q.x));
      float fg  = quantU8(sigmoid_fast(q.y));
      float cg  = quantS8(tanh_fast(q.z));
      float og  = quantU8(sigmoid_fast(q.w));
      float c0  = cx[oidx];
      float cyv = quantS8((quantS8(fg * c0) + quantS8(ing * cg)) * 0.5f);
      float hyv = quantS8(og * quantS8(tanh_fast(cyv * 2.0f)));
      hy[oidx] = hyv;
      cy[oidx] = cyv;
    }
  }
}

// ---------------- host ----------------
extern "C" void kernel_launch(void* const* d_in, const int* in_sizes, int n_in,
                              void* d_out, int out_size, void* d_ws, size_t ws_size,
                              hipStream_t stream)
{
  const float* input = (const float*)d_in[0];
  const float* hx    = (const float*)d_in[1];
  const float* cx    = (const float*)d_in[2];
  const float* wih   = (const float*)d_in[3];
  const float* whh   = (const float*)d_in[4];
  const float* bih   = (const float*)d_in[5];
  const float* bhh   = (const float*)d_in[6];
  (void)in_sizes; (void)n_in; (void)ws_size;

  uint8_t* ws = (uint8_t*)d_ws;
  unsigned short* A   = (unsigned short*)(ws + WS_A_OFF);
  unsigned short* B   = (unsigned short*)(ws + WS_B_OFF);
  float* biasE        = (float*)(ws + WS_BIAS_OFF);
  uint32_t* mx        = (uint32_t*)(ws + WS_MAX_OFF);

  uint32_t nk[4][2];
#if PART
  for (int i = 0; i < 4; ++i) tf2x32(0u, 42u, 0u, (uint32_t)i, nk[i][0], nk[i][1]);
#else
  {
    uint32_t w0[4], w1[4];
    for (int i = 0; i < 4; ++i) tf2x32(0u, 42u, (uint32_t)i, (uint32_t)(i + 4), w0[i], w1[i]);
    uint32_t out8[8] = {w0[0], w0[1], w0[2], w0[3], w1[0], w1[1], w1[2], w1[3]};
    for (int i = 0; i < 4; ++i) { nk[i][0] = out8[2 * i]; nk[i][1] = out8[2 * i + 1]; }
  }
#endif

  init_max<<<1, 64, 0, stream>>>(mx);
  kmax_all<<<2056, 256, 0, stream>>>((const float4*)wih, (const float4*)whh,
                                     (const float4*)bih, (const float4*)bhh, mx);
  build_all<<<40976, 256, 0, stream>>>(wih, whh, (const float4*)input, (const float4*)hx,
                                       bih, bhh, A, B, biasE, mx,
                                       nk[0][0], nk[0][1], nk[1][0], nk[1][1],
                                       nk[2][0], nk[2][1], nk[3][0], nk[3][1]);

  float* hy = (float*)d_out;
  float* cyp = hy + (size_t)BATCH * 1024;

  (void)hipFuncSetAttribute((const void*)gemm_gates,
                            hipFuncAttributeMaxDynamicSharedMemorySize, 147456);
  gemm_gates<<<dim3(256), dim3(512), 147456, stream>>>(A, B, biasE, cx, hy, cyp);
}